// Round 1
// baseline (226.399 us; speedup 1.0000x reference)
//
#include <hip/hip_runtime.h>

// out[b,f,d] = x[b,f] * W[f,d] + b[f,d]
// B=16384, F=64, D=192, fp32. Output 805 MB -> HBM-write-bound.
// Flat float4 grid-stride: D=192 -> 48 float4 per (b,f) row.

#define TOTAL4 (16384 * 64 * 48)   // output element count / 4

__global__ __launch_bounds__(256) void ftemb_kernel(
    const float*  __restrict__ x,    // [B*F]
    const float4* __restrict__ W,    // [F*48]
    const float4* __restrict__ Bb,   // [F*48]
    float4*       __restrict__ out,  // [B*F*48]
    int total4)
{
    int i = blockIdx.x * blockDim.x + threadIdx.x;
    const int stride = gridDim.x * blockDim.x;
    for (; i < total4; i += stride) {
        int row = i / 48;            // b*64 + f  (magic-mul)
        int c   = i - row * 48;      // float4 column within row
        int f   = row & 63;
        float xs  = x[row];          // L2-cached, reused 48x per row
        float4 w  = W[f * 48 + c];   // 96 KB total W+b -> L2-resident
        float4 bb = Bb[f * 48 + c];
        float4 o;
        o.x = fmaf(xs, w.x, bb.x);
        o.y = fmaf(xs, w.y, bb.y);
        o.z = fmaf(xs, w.z, bb.z);
        o.w = fmaf(xs, w.w, bb.w);
        out[i] = o;                  // coalesced 16 B/lane store
    }
}

extern "C" void kernel_launch(void* const* d_in, const int* in_sizes, int n_in,
                              void* d_out, int out_size, void* d_ws, size_t ws_size,
                              hipStream_t stream) {
    const float*  x  = (const float*)d_in[0];
    const float4* W  = (const float4*)d_in[1];
    const float4* Bb = (const float4*)d_in[2];
    float4* out = (float4*)d_out;

    const int total4 = out_size / 4;   // 50,331,648
    const int threads = 256;
    const int blocks  = 2048;          // grid-stride, 96 iters/thread
    ftemb_kernel<<<blocks, threads, 0, stream>>>(x, W, Bb, out, total4);
}